// Round 4
// baseline (1160.522 us; speedup 1.0000x reference)
//
#include <hip/hip_runtime.h>

#define N_NODES 50000
#define N_EDGES 800000
#define EMB 96
#define HID 192

#define NB 512          // 2 blocks/CU x 256 CUs -> capacity == grid, all resident
#define NT 256
#define GSIZE (NB * NT)

typedef __attribute__((ext_vector_type(8))) short short8;
typedef __attribute__((ext_vector_type(4))) float f32x4;
typedef __attribute__((ext_vector_type(4))) unsigned short ushort4v;

static __device__ __forceinline__ unsigned short f2bf(float f) {
    union { float f; unsigned int u; } v; v.f = f;
    unsigned int u = v.u;
    return (unsigned short)((u + 0x7FFFu + ((u >> 16) & 1u)) >> 16);
}

struct Params {
    const float* h; const float* ea; const int* src; const int* dst;
    const float* W1; const float* b1; const float* W2; const float* b2;
    const float* eps; float* out;
    unsigned short* aggr_bf; unsigned short* W1t; unsigned short* W2t;
    int2* pairs; int* offsets; int* counts; int* cursor;
    int* bar;            // [0]=arrive, [1]=generation (zeroed each launch)
    int* bsum; int* bpref;
};

// Sense-reversal grid barrier (what grid.sync() does internally, minus the
// cooperative-launch API). Requires all NB blocks resident: guaranteed by
// capacity arithmetic (LDS 64KB -> 2/CU, launch_bounds(256,2) -> VGPR<=256).
static __device__ __forceinline__ void grid_barrier(int* arrive, int* gen) {
    __syncthreads();                       // block's stores drained (vmcnt 0)
    if (threadIdx.x == 0) {
        int g = __hip_atomic_load(gen, __ATOMIC_RELAXED, __HIP_MEMORY_SCOPE_AGENT);
        __threadfence();                   // release to device scope
        int prev = __hip_atomic_fetch_add(arrive, 1, __ATOMIC_ACQ_REL,
                                          __HIP_MEMORY_SCOPE_AGENT);
        if (prev == NB - 1) {
            __hip_atomic_store(arrive, 0, __ATOMIC_RELAXED, __HIP_MEMORY_SCOPE_AGENT);
            __hip_atomic_fetch_add(gen, 1, __ATOMIC_RELEASE, __HIP_MEMORY_SCOPE_AGENT);
        } else {
            while (__hip_atomic_load(gen, __ATOMIC_ACQUIRE,
                                     __HIP_MEMORY_SCOPE_AGENT) == g)
                __builtin_amdgcn_s_sleep(1);
        }
    }
    __syncthreads();
    __threadfence();                       // acquire side for all threads
}

// LDS: [0,39936) W1 tile [192][104] shorts (scan scratch early);
//      [39936,65536) 4 per-wave hidden tiles [16][200] shorts.
__global__ __launch_bounds__(NT, 2) void mega_kernel(Params p)
{
    __shared__ __attribute__((aligned(16))) unsigned char smem[65536];
    const int t = threadIdx.x, b = blockIdx.x;
    const int gid = b * NT + t;
    const int lane = t & 63, wave = t >> 6;

    // ---------------- P1: dst histogram + weight transpose->bf16 ---------------
    for (int e = gid; e < N_EDGES; e += GSIZE)
        atomicAdd(&p.counts[p.dst[e]], 1);
    for (int i = gid; i < EMB * HID; i += GSIZE) {       // W1t: [HID][EMB]
        int n = i / EMB, k = i - n * EMB;
        p.W1t[i] = f2bf(p.W1[(size_t)k * HID + n]);
    }
    for (int i = gid; i < EMB * HID; i += GSIZE) {       // W2t: [EMB][HID]
        int n = i / HID, k = i - n * HID;
        p.W2t[i] = f2bf(p.W2[(size_t)k * EMB + n]);
    }
    grid_barrier(&p.bar[0], &p.bar[1]);

    // ---------------- P2a: block-local exclusive scan (256 counts/block) -------
    int* ws4 = (int*)smem;
    int v = (gid < N_NODES) ? p.counts[gid] : 0;
    int x = v;
    #pragma unroll
    for (int d = 1; d < 64; d <<= 1) { int y = __shfl_up(x, d); if (lane >= d) x += y; }
    if (lane == 63) ws4[wave] = x;
    __syncthreads();
    int s0 = ws4[0], s1 = ws4[1], s2 = ws4[2], s3 = ws4[3];
    int wbase = (wave > 0 ? s0 : 0) + (wave > 1 ? s1 : 0) + (wave > 2 ? s2 : 0);
    int locex = wbase + x - v;                           // persists in registers
    if (t == 0) p.bsum[b] = s0 + s1 + s2 + s3;
    grid_barrier(&p.bar[0], &p.bar[1]);

    // ---------------- P2b: block 0 scans the NB block sums ---------------------
    if (b == 0) {
        int carry = 0;
        #pragma unroll
        for (int half = 0; half < NB / NT; ++half) {
            int a = p.bsum[half * NT + t];
            int xx = a;
            #pragma unroll
            for (int d = 1; d < 64; d <<= 1) { int y = __shfl_up(xx, d); if (lane >= d) xx += y; }
            if (lane == 63) ws4[wave] = xx;
            __syncthreads();
            int q0 = ws4[0], q1 = ws4[1], q2 = ws4[2], q3 = ws4[3];
            int wb = (wave > 0 ? q0 : 0) + (wave > 1 ? q1 : 0) + (wave > 2 ? q2 : 0);
            p.bpref[half * NT + t] = carry + wb + xx - a;
            __syncthreads();
            carry += q0 + q1 + q2 + q3;
        }
    }
    grid_barrier(&p.bar[0], &p.bar[1]);

    // ---------------- P2c: write offsets ---------------------------------------
    if (gid < N_NODES) p.offsets[gid] = p.bpref[b] + locex;
    if (gid == 0) p.offsets[N_NODES] = N_EDGES;
    grid_barrier(&p.bar[0], &p.bar[1]);

    // ---------------- P3: fill CSR buckets with (edge_id, src) -----------------
    for (int e = gid; e < N_EDGES; e += GSIZE) {
        int d = p.dst[e];
        int pos = p.offsets[d] + atomicAdd(&p.cursor[d], 1);
        p.pairs[pos] = make_int2(e, p.src[e]);
    }
    grid_barrier(&p.bar[0], &p.bar[1]);

    // ---------------- P4: gather-reduce (32-lane groups, 24 active) ------------
    {
        const f32x4* h4 = (const f32x4*)p.h;
        const f32x4* ea4 = (const f32x4*)p.ea;
        int g = t >> 5, c = t & 31;
        for (int n = b * 8 + g; n < N_NODES; n += NB * 8) {
            int beg = p.offsets[n], end = p.offsets[n + 1];
            if (c < 24) {
                f32x4 a0 = {0.f, 0.f, 0.f, 0.f}, a1 = a0, a2 = a0, a3 = a0;
                int i = beg;
                for (; i + 4 <= end; i += 4) {
                    int2 q0 = p.pairs[i], q1 = p.pairs[i + 1];
                    int2 q2 = p.pairs[i + 2], q3 = p.pairs[i + 3];
                    f32x4 e0 = __builtin_nontemporal_load(&ea4[(size_t)q0.x * 24 + c]);
                    f32x4 e1 = __builtin_nontemporal_load(&ea4[(size_t)q1.x * 24 + c]);
                    f32x4 e2 = __builtin_nontemporal_load(&ea4[(size_t)q2.x * 24 + c]);
                    f32x4 e3 = __builtin_nontemporal_load(&ea4[(size_t)q3.x * 24 + c]);
                    f32x4 g0 = h4[(size_t)q0.y * 24 + c];
                    f32x4 g1 = h4[(size_t)q1.y * 24 + c];
                    f32x4 g2 = h4[(size_t)q2.y * 24 + c];
                    f32x4 g3 = h4[(size_t)q3.y * 24 + c];
                    a0 += e0 + g0;
                    a1 += e1 + g1;
                    a2 += e2 + g2;
                    a3 += e3 + g3;
                }
                for (; i < end; ++i) {
                    int2 q = p.pairs[i];
                    f32x4 e = __builtin_nontemporal_load(&ea4[(size_t)q.x * 24 + c]);
                    f32x4 gg = h4[(size_t)q.y * 24 + c];
                    a0 += e + gg;
                }
                f32x4 acc = (a0 + a1) + (a2 + a3);
                ushort4v o;
                o.x = f2bf(acc.x); o.y = f2bf(acc.y);
                o.z = f2bf(acc.z); o.w = f2bf(acc.w);
                *(ushort4v*)(p.aggr_bf + (size_t)n * EMB + c * 4) = o;
            }
        }
    }
    grid_barrier(&p.bar[0], &p.bar[1]);

    // ---------------- P5: fused 2-layer MLP + residual -------------------------
    {
        unsigned short* sW1 = (unsigned short*)smem;                 // [192][104]
        unsigned short* sHid = (unsigned short*)(smem + HID * 104 * 2);
        const unsigned int* p1 = (const unsigned int*)p.W1t;
        for (int i = t; i < HID * (EMB / 2); i += NT) {
            int n = i / (EMB / 2), c2 = i - n * (EMB / 2);
            *(unsigned int*)&sW1[n * 104 + c2 * 2] = p1[n * (EMB / 2) + c2];
        }
        __syncthreads();
        int quad = lane >> 4, col = lane & 15;
        float s = 1.f + p.eps[0];
        unsigned short* sH = sHid + wave * (16 * 200);               // private tile
        for (int rb = b; rb < (N_NODES + 63) / 64; rb += NB) {
            int m0 = rb * 64 + wave * 16;
            if (m0 >= N_NODES) continue;
            int m = m0 + col;

            f32x4 acc1[12];
            #pragma unroll
            for (int c = 0; c < 12; ++c) acc1[c] = (f32x4){0.f, 0.f, 0.f, 0.f};
            #pragma unroll
            for (int ks = 0; ks < 3; ++ks) {
                short8 af = *(const short8*)(p.aggr_bf + (size_t)m * EMB + ks * 32 + quad * 8);
                #pragma unroll
                for (int c = 0; c < 12; ++c) {
                    short8 bf = *(const short8*)(sW1 + (c * 16 + col) * 104 + ks * 32 + quad * 8);
                    acc1[c] = __builtin_amdgcn_mfma_f32_16x16x32_bf16(af, bf, acc1[c], 0, 0, 0);
                }
            }
            #pragma unroll
            for (int c = 0; c < 12; ++c) {
                float bias = p.b1[c * 16 + col];
                #pragma unroll
                for (int r = 0; r < 4; ++r) {
                    int lr = quad * 4 + r;
                    sH[lr * 200 + c * 16 + col] = f2bf(fmaxf(acc1[c][r] + bias, 0.f));
                }
            }
            f32x4 acc2[6];
            #pragma unroll
            for (int c = 0; c < 6; ++c) acc2[c] = (f32x4){0.f, 0.f, 0.f, 0.f};
            #pragma unroll
            for (int ks = 0; ks < 6; ++ks) {
                short8 af = *(const short8*)(sH + col * 200 + ks * 32 + quad * 8);
                #pragma unroll
                for (int c = 0; c < 6; ++c) {
                    short8 bf = *(const short8*)(p.W2t + (size_t)(c * 16 + col) * HID + ks * 32 + quad * 8);
                    acc2[c] = __builtin_amdgcn_mfma_f32_16x16x32_bf16(af, bf, acc2[c], 0, 0, 0);
                }
            }
            #pragma unroll
            for (int c = 0; c < 6; ++c) {
                float bias = p.b2[c * 16 + col];
                #pragma unroll
                for (int r = 0; r < 4; ++r) {
                    int row = m0 + quad * 4 + r;
                    size_t idx = (size_t)row * EMB + c * 16 + col;
                    p.out[idx] = acc2[c][r] + bias + s * p.h[idx];
                }
            }
        }
    }
}

extern "C" void kernel_launch(void* const* d_in, const int* in_sizes, int n_in,
                              void* d_out, int out_size, void* d_ws, size_t ws_size,
                              hipStream_t stream) {
    Params p;
    p.h   = (const float*)d_in[0];
    p.ea  = (const float*)d_in[1];
    p.src = (const int*)d_in[2];
    p.dst = (const int*)d_in[3];
    p.W1  = (const float*)d_in[4];
    p.b1  = (const float*)d_in[5];
    p.W2  = (const float*)d_in[6];
    p.b2  = (const float*)d_in[7];
    p.eps = (const float*)d_in[8];
    p.out = (float*)d_out;

    unsigned char* wsp = (unsigned char*)d_ws;
    p.aggr_bf = (unsigned short*)wsp; wsp += (size_t)N_NODES * EMB * 2;
    p.W1t     = (unsigned short*)wsp; wsp += (size_t)EMB * HID * 2;
    p.W2t     = (unsigned short*)wsp; wsp += (size_t)EMB * HID * 2;
    p.pairs   = (int2*)wsp; wsp += (size_t)N_EDGES * sizeof(int2);
    p.offsets = (int*)wsp;  wsp += (size_t)(N_NODES + 1) * sizeof(int);
    p.counts  = (int*)wsp;  wsp += (size_t)N_NODES * sizeof(int);
    p.cursor  = (int*)wsp;  wsp += (size_t)N_NODES * sizeof(int);
    p.bar     = (int*)wsp;  wsp += 2 * sizeof(int);
    p.bsum    = (int*)wsp;  wsp += (size_t)NB * sizeof(int);
    p.bpref   = (int*)wsp;

    // zero counts + cursor + barrier state (contiguous; workspace is poisoned
    // between iterations, so bar MUST be re-zeroed every launch)
    hipMemsetAsync(p.counts, 0, ((size_t)2 * N_NODES + 2) * sizeof(int), stream);

    hipLaunchKernelGGL(mega_kernel, dim3(NB), dim3(NT), 0, stream, p);
}